// Round 15
// baseline (405.832 us; speedup 1.0000x reference)
//
#include <hip/hip_runtime.h>
#include <hip/hip_bf16.h>

// Resolved: x,W*,a*,b* fp32 | indices int32 | d_out FLOAT32.
// r13-r17: fused agg (shifted-exp softmax), fp16 pipeline, LDS-tiled MFMA GEMM
//          with fused alpha epilogue.
// r22: gemm wave remap -> REGRESSION. r26: A-prefetch -> REGRESSION (+96 VGPR
//      ate occupancy). Root cause identified: grid = N/128 = 391 blocks on
//      256 CUs -> ~1 wave/SIMD, no TLP to hide ~900cy HBM latency.
// r24: counter padding -> NO-OP (memory-side atomic transaction rate).
// r25: CSR build = two-level counting sort, LDS atomics only (-67us).
// r27: BM templated, all gemms BM=64 (M_rep=1): grid 391 -> 782 blocks
//      (~3 blocks/CU, LDS-capped 3 for gemm1), acc halves to 64 VGPR.
//      B-stage traffic doubles but is L2-resident. Bit-identical math.

using halfx8  = __attribute__((ext_vector_type(8))) _Float16;
using floatx4 = __attribute__((ext_vector_type(4))) float;

__device__ __forceinline__ float lrelu(float v) { return v > 0.f ? v : 0.2f * v; }

__device__ __forceinline__ int ld_idx32(const int* __restrict__ p, size_t i, int N) {
    int v = p[i];
    return ((unsigned)v < (unsigned)N) ? v : 0;
}
__device__ __forceinline__ void edge_sd(const int* __restrict__ ei, int E, int N, int e, int& s,
                                        int& d) {
    if (e < E) {
        s = ld_idx32(ei, e, N);
        d = ld_idx32(ei, (size_t)E + e, N);
    } else {
        s = d = e - E;  // self-loop
    }
}

#define WTOT (384 * 256 + 256 * 64 + 64 * 128)
#define EPB 4096  // edges per block in bucket passes

// ---------- weight transpose+convert: Wt[o][k] = f16(W[k][o]) ----------
__global__ void tr_k(const float* __restrict__ W1, const float* __restrict__ W2,
                     const float* __restrict__ W3, _Float16* __restrict__ Wt1,
                     _Float16* __restrict__ Wt2, _Float16* __restrict__ Wt3) {
    int j = blockIdx.x * 256 + threadIdx.x;
    if (j < 384 * 256) {
        int k = j / 256, o = j % 256;
        Wt1[(size_t)o * 384 + k] = (_Float16)W1[j];
    } else if (j < 384 * 256 + 256 * 64) {
        int jj = j - 384 * 256;
        int k = jj / 64, o = jj % 64;
        Wt2[(size_t)o * 256 + k] = (_Float16)W2[jj];
    } else if (j < WTOT) {
        int jj = j - (384 * 256 + 256 * 64);
        int k = jj / 128, o = jj % 128;
        Wt3[(size_t)o * 64 + k] = (_Float16)W3[jj];
    }
}

// ---------- CSR build: two-level counting sort, LDS atomics only ----------
// Requires N <= 65536 (bucket = d>>8 in [0,256)).
__global__ __launch_bounds__(256) void hist1_k(const int* __restrict__ ei, int E, int N,
                                               int* __restrict__ histG, int NBE) {
    __shared__ int h[256];
    const int t = threadIdx.x, b = blockIdx.x;
    h[t] = 0;
    __syncthreads();
    const int ET = E + N;
    const int base = b * EPB;
    for (int i = t; i < EPB; i += 256) {
        int e = base + i;
        if (e < ET) {
            int d = (e < E) ? ld_idx32(ei, (size_t)E + e, N) : (e - E);
            atomicAdd(&h[d >> 8], 1);
        }
    }
    __syncthreads();
    histG[(size_t)t * NBE + b] = h[t];  // bucket-major
}
// scan pass 1: per-256-chunk sums
__global__ void scan1_k(const int* __restrict__ a, int* __restrict__ part, int M) {
    __shared__ int sm[256];
    int t = threadIdx.x;
    int i = blockIdx.x * 256 + t;
    sm[t] = (i < M) ? a[i] : 0;
    __syncthreads();
    for (int off = 128; off > 0; off >>= 1) {
        if (t < off) sm[t] += sm[t + off];
        __syncthreads();
    }
    if (t == 0) part[blockIdx.x] = sm[0];
}
// scan pass 2: exclusive scan (block base = parallel sum of part[0..b))
__global__ void scan2_k(const int* __restrict__ a, const int* __restrict__ part,
                        int* __restrict__ out, int M) {
    __shared__ int sm[256];
    __shared__ int base_sh;
    const int t = threadIdx.x, b = blockIdx.x;
    int p = 0;
    for (int j = t; j < b; j += 256) p += part[j];
    sm[t] = p;
    __syncthreads();
    for (int off = 128; off > 0; off >>= 1) {
        if (t < off) sm[t] += sm[t + off];
        __syncthreads();
    }
    if (t == 0) base_sh = sm[0];
    __syncthreads();
    const int base = base_sh;
    int i = b * 256 + t;
    int v = (i < M) ? a[i] : 0;
    sm[t] = v;
    __syncthreads();
    for (int off = 1; off < 256; off <<= 1) {
        int add = (t >= off) ? sm[t - off] : 0;
        __syncthreads();
        sm[t] += add;
        __syncthreads();
    }
    if (i < M) out[i] = base + sm[t] - v;
}
// scatter edges into bucket-partitioned (s,d) pairs; LDS counters
__global__ __launch_bounds__(256) void scatter_k(const int* __restrict__ ei, int E, int N,
                                                 const int* __restrict__ histS, int NBE,
                                                 int2* __restrict__ ep) {
    __shared__ int ofs[256];
    const int t = threadIdx.x, b = blockIdx.x;
    ofs[t] = histS[(size_t)t * NBE + b];
    __syncthreads();
    const int ET = E + N;
    const int base = b * EPB;
    for (int i = t; i < EPB; i += 256) {
        int e = base + i;
        if (e < ET) {
            int s, d;
            edge_sd(ei, E, N, e, s, d);
            int pos = atomicAdd(&ofs[d >> 8], 1);
            ep[pos] = make_int2(s, d);
        }
    }
}
// per-bucket CSR: 256 dsts per block; LDS count + scan + place
__global__ __launch_bounds__(256) void csrb_k(const int* __restrict__ histS, int NBE,
                                              const int2* __restrict__ ep, int* __restrict__ csr,
                                              int* __restrict__ rowptr, int N, int ET) {
    __shared__ int cnt[256], rb[256], sm[256];
    const int t = threadIdx.x, c = blockIdx.x;
    const int lo = histS[(size_t)c * NBE];
    const int hi = (c + 1 < 256) ? histS[(size_t)(c + 1) * NBE] : ET;
    cnt[t] = 0;
    __syncthreads();
    for (int i = lo + t; i < hi; i += 256) atomicAdd(&cnt[ep[i].y & 255], 1);
    __syncthreads();
    int v = cnt[t];
    sm[t] = v;
    __syncthreads();
    for (int off = 1; off < 256; off <<= 1) {
        int add = (t >= off) ? sm[t - off] : 0;
        __syncthreads();
        sm[t] += add;
        __syncthreads();
    }
    rb[t] = lo + sm[t] - v;  // row base for dst c*256+t
    int dg = c * 256 + t;
    if (dg < N) rowptr[dg] = rb[t];
    if (dg == N - 1) rowptr[N] = ET;
    cnt[t] = 0;
    __syncthreads();
    for (int i = lo + t; i < hi; i += 256) {
        int2 e = ep[i];
        int d8 = e.y & 255;
        int p = atomicAdd(&cnt[d8], 1);
        csr[rb[d8] + p] = e.x;
    }
}

// ---------- LDS-tiled MFMA f16 GEMM + fused alpha epilogue ----------
// Block: 256 thr / 4 waves, BM rows (wave w owns rows blk*BM + w*(BM/4), MR=BM/64).
// Bt staged in LDS in K-chunks of KC, rows padded +16B.
// Epilogue: C fp16 + per-row per-head dots with a_s/a_d -> alpha_s/alpha_d.
template <int K, int O, int KC, int BM, bool AF32>
__global__ __launch_bounds__(256, 2) void gemm_mfma(const void* __restrict__ A,
                                                    const _Float16* __restrict__ Bt,
                                                    _Float16* __restrict__ C,
                                                    const float* __restrict__ aw_s,
                                                    const float* __restrict__ aw_d,
                                                    float* __restrict__ alpha_s,
                                                    float* __restrict__ alpha_d, int M) {
    constexpr int MR = BM / 64;      // 16-row tiles per wave
    constexpr int NT = O / 16;
    constexpr int TPH = NT / 4;      // t-values per head
    constexpr int RB = KC * 2 + 16;  // padded LDS row bytes
    constexpr int SPR = KC / 8;      // 16B segments per row
    __shared__ __align__(16) char bs[O * RB];
    const int tid = threadIdx.x;
    const int wave = tid >> 6, lane = tid & 63;
    const int col = lane & 15, quad = lane >> 4;
    const int m0 = blockIdx.x * BM + wave * (MR * 16);
    int ar[MR];
#pragma unroll
    for (int m = 0; m < MR; ++m) {
        int r = m0 + m * 16 + col;
        ar[m] = (r < M) ? r : M - 1;  // clamp: clamped-row outputs are discarded
    }
    floatx4 acc[MR][NT];
#pragma unroll
    for (int m = 0; m < MR; ++m)
#pragma unroll
        for (int t = 0; t < NT; ++t) acc[m][t] = (floatx4){0.f, 0.f, 0.f, 0.f};
    const float* Af[MR];
    const _Float16* Ah[MR];
#pragma unroll
    for (int m = 0; m < MR; ++m) {
        Af[m] = reinterpret_cast<const float*>(A) + (size_t)ar[m] * K + quad * 8;
        Ah[m] = reinterpret_cast<const _Float16*>(A) + (size_t)ar[m] * K + quad * 8;
    }

    for (int kc = 0; kc < K; kc += KC) {
        __syncthreads();  // protect previous chunk's reads
        // cooperative stage: Bt[0..O)[kc..kc+KC) -> bs, row-major, padded rows
        for (int i = tid; i < O * SPR; i += 256) {
            int o = i / SPR, seg = i % SPR;
            float4 v = *reinterpret_cast<const float4*>(reinterpret_cast<const char*>(Bt) +
                                                        (size_t)o * (K * 2) + (size_t)kc * 2 +
                                                        seg * 16);
            *reinterpret_cast<float4*>(&bs[o * RB + seg * 16]) = v;
        }
        __syncthreads();
#pragma unroll
        for (int kb = 0; kb < KC; kb += 32) {
            halfx8 a[MR];
            if constexpr (AF32) {
#pragma unroll
                for (int m = 0; m < MR; ++m) {
                    float4 u = *reinterpret_cast<const float4*>(Af[m] + kc + kb);
                    float4 v = *reinterpret_cast<const float4*>(Af[m] + kc + kb + 4);
                    a[m][0] = (_Float16)u.x; a[m][1] = (_Float16)u.y;
                    a[m][2] = (_Float16)u.z; a[m][3] = (_Float16)u.w;
                    a[m][4] = (_Float16)v.x; a[m][5] = (_Float16)v.y;
                    a[m][6] = (_Float16)v.z; a[m][7] = (_Float16)v.w;
                }
            } else {
#pragma unroll
                for (int m = 0; m < MR; ++m)
                    a[m] = *reinterpret_cast<const halfx8*>(Ah[m] + kc + kb);
            }
#pragma unroll
            for (int t = 0; t < NT; ++t) {
                halfx8 b = *reinterpret_cast<const halfx8*>(
                    &bs[(size_t)(t * 16 + col) * RB + kb * 2 + quad * 16]);
#pragma unroll
                for (int m = 0; m < MR; ++m)
                    acc[m][t] = __builtin_amdgcn_mfma_f32_16x16x32_f16(a[m], b, acc[m][t], 0, 0, 0);
            }
        }
    }
    // C write (fp16)
#pragma unroll
    for (int m = 0; m < MR; ++m)
#pragma unroll
        for (int t = 0; t < NT; ++t)
#pragma unroll
            for (int r = 0; r < 4; ++r) {
                int row = m0 + m * 16 + quad * 4 + r;
                if (row < M) C[(size_t)row * O + t * 16 + col] = (_Float16)acc[m][t][r];
            }
    // fused alpha: per row, per head dots with a_s/a_d (flat index == channel o)
    float ws[NT], wd[NT];
#pragma unroll
    for (int t = 0; t < NT; ++t) {
        ws[t] = aw_s[t * 16 + col];
        wd[t] = aw_d[t * 16 + col];
    }
#pragma unroll
    for (int m = 0; m < MR; ++m)
#pragma unroll
        for (int r = 0; r < 4; ++r) {
            float sh[4] = {0.f, 0.f, 0.f, 0.f}, dh[4] = {0.f, 0.f, 0.f, 0.f};
#pragma unroll
            for (int t = 0; t < NT; ++t) {
                float v = acc[m][t][r];
                sh[t / TPH] = fmaf(v, ws[t], sh[t / TPH]);
                dh[t / TPH] = fmaf(v, wd[t], dh[t / TPH]);
            }
#pragma unroll
            for (int off = 1; off < 16; off <<= 1) {
#pragma unroll
                for (int hh = 0; hh < 4; ++hh) {
                    sh[hh] += __shfl_xor(sh[hh], off);
                    dh[hh] += __shfl_xor(dh[hh], off);
                }
            }
            int row = m0 + m * 16 + quad * 4 + r;
            if (col == 0 && row < M) {
                *reinterpret_cast<float4*>(alpha_s + (size_t)row * 4) =
                    make_float4(sh[0], sh[1], sh[2], sh[3]);
                *reinterpret_cast<float4*>(alpha_d + (size_t)row * 4) =
                    make_float4(dh[0], dh[1], dh[2], dh[3]);
            }
        }
}

// ---------- fused CSR attention: shifted-exp softmax (no max), fp16 gather ----------
// ex = exp(e - 16): scores bounded -> overflow-safe, alpha ratio unchanged.
// Denominator: per-lane partials, ONE butterfly at the end.
// Lane loads 8 halves (16B) of row lane/LPR; R=64/LPR rows per load instruction.
// MODE 0: +bias, ELU, fp16 out (layers 1,2). MODE 1: mean-over-heads +bias, fp32 z.
template <int O, int MODE>
__global__ __launch_bounds__(256) void agg_csr(const int* __restrict__ rowptr,
                                               const int* __restrict__ csr,
                                               const _Float16* __restrict__ h,
                                               const float* __restrict__ as_,
                                               const float* __restrict__ ad_,
                                               const float* __restrict__ bias,
                                               void* __restrict__ outp, int N) {
    constexpr int LPR = O / 8;   // lanes per row (8 halves = 16B each)
    constexpr int R = 64 / LPR;  // rows per load instruction (2/8/4 for O=256/64/128)
    constexpr int CH = O / 4;    // channels per head
    __shared__ float ex_lds[4][64][4];
    const int lane = threadIdx.x & 63;
    const int wave = threadIdx.x >> 6;
    const int d = blockIdx.x * 4 + wave;
    if (d >= N) return;
    const int g = lane / LPR;        // row subgroup
    const int c0 = (lane % LPR) * 8; // channel base (8 channels, all in one head)
    const int hd = c0 / CH;          // head of this lane's channels
    const int r0 = rowptr[d], r1 = rowptr[d + 1];
    const float4 adv = *reinterpret_cast<const float4*>(ad_ + (size_t)d * 4);

    float4 den_l = make_float4(0.f, 0.f, 0.f, 0.f);  // per-lane partial denominators
    float acc[8];
#pragma unroll
    for (int q = 0; q < 8; ++q) acc[q] = 0.f;
    float(&exw)[64][4] = ex_lds[wave];

    for (int base = r0; base < r1; base += 64) {
        const int cnt = min(64, r1 - base);
        const bool valid = lane < cnt;
        int s_l = 0;
        float4 av = make_float4(0.f, 0.f, 0.f, 0.f);
        if (valid) {
            s_l = csr[base + lane];
            av = *reinterpret_cast<const float4*>(as_ + (size_t)s_l * 4);
        }
        const int iters = (cnt + R - 1) / R;

        auto ldrow = [&](int i) -> halfx8 {
            int e = i * R + g;
            int idx = (e < cnt) ? e : (cnt - 1);
            int s = __shfl(s_l, idx);
            return *reinterpret_cast<const halfx8*>(h + (size_t)s * O + c0);
        };
        // issue first 4 row loads now: depend only on csr; overlap exp+LDS-write
        halfx8 b0 = ldrow(0), b1 = ldrow(1), b2 = ldrow(2), b3 = ldrow(3);

        float4 ex4 = make_float4(0.f, 0.f, 0.f, 0.f);
        if (valid) {
            ex4.x = __expf(lrelu(av.x + adv.x) - 16.f);
            ex4.y = __expf(lrelu(av.y + adv.y) - 16.f);
            ex4.z = __expf(lrelu(av.z + adv.z) - 16.f);
            ex4.w = __expf(lrelu(av.w + adv.w) - 16.f);
        }
        den_l.x += ex4.x; den_l.y += ex4.y; den_l.z += ex4.z; den_l.w += ex4.w;
        *reinterpret_cast<float4*>(&exw[lane][0]) = ex4;  // zeros past cnt

        auto accrow = [&](int i, halfx8 src) {
            int e = i * R + g;
            float ex = exw[e][hd];
#pragma unroll
            for (int q = 0; q < 8; ++q) acc[q] = fmaf(ex, (float)src[q], acc[q]);
        };
        int i = 0;
        for (; i + 4 < iters; i += 4) {
            accrow(i, b0);     b0 = ldrow(i + 4);
            accrow(i + 1, b1); b1 = ldrow(i + 5);
            accrow(i + 2, b2); b2 = ldrow(i + 6);
            accrow(i + 3, b3); b3 = ldrow(i + 7);
        }
        if (i < iters)     accrow(i, b0);
        if (i + 1 < iters) accrow(i + 1, b1);
        if (i + 2 < iters) accrow(i + 2, b2);
        if (i + 3 < iters) accrow(i + 3, b3);
    }

    // single denominator butterfly (all 4 heads), once per dst
#pragma unroll
    for (int off = 1; off < 64; off <<= 1) {
        den_l.x += __shfl_xor(den_l.x, off);
        den_l.y += __shfl_xor(den_l.y, off);
        den_l.z += __shfl_xor(den_l.z, off);
        den_l.w += __shfl_xor(den_l.w, off);
    }

    // fold cross-group partial sums (groups live in high lane bits)
#pragma unroll
    for (int q = 0; q < 8; ++q) {
        if constexpr (R >= 8) acc[q] += __shfl_xor(acc[q], 8);
        if constexpr (R >= 4) acc[q] += __shfl_xor(acc[q], 16);
        if constexpr (R >= 2) acc[q] += __shfl_xor(acc[q], 32);
    }

    float den = (hd == 0 ? den_l.x : (hd == 1 ? den_l.y : (hd == 2 ? den_l.z : den_l.w))) + 1e-30f;
    float v[8];
#pragma unroll
    for (int q = 0; q < 8; ++q) v[q] = acc[q] / den;

    if constexpr (MODE == 0) {  // +bias, ELU, fp16 act out
#pragma unroll
        for (int q = 0; q < 8; ++q) {
            float t = v[q] + bias[c0 + q];
            v[q] = t > 0.f ? t : (__expf(t) - 1.f);
        }
        if (g == 0) {
            halfx8 o;
#pragma unroll
            for (int q = 0; q < 8; ++q) o[q] = (_Float16)v[q];
            *reinterpret_cast<halfx8*>((_Float16*)outp + (size_t)d * O + c0) = o;
        }
    } else {  // MODE 1: mean over heads + bias -> fp32 z (O=128: heads at lane%16 stride 4)
#pragma unroll
        for (int q = 0; q < 8; ++q) {
            v[q] += __shfl_xor(v[q], 4);
            v[q] += __shfl_xor(v[q], 8);
        }
        if (lane < 4) {
            float* zp = (float*)outp + (size_t)d * 32 + lane * 8;
#pragma unroll
            for (int q = 0; q < 8; ++q) zp[q] = 0.25f * v[q] + bias[lane * 8 + q];
        }
    }
}

// ---------- decoder: 8 lanes per pair, coalesced float4 reads ----------
__global__ __launch_bounds__(256) void logits8_k(const int* __restrict__ eli, int EC, int N,
                                                 const float* __restrict__ z,
                                                 float* __restrict__ outp) {
    int i = blockIdx.x * 32 + (threadIdx.x >> 3);  // pair index
    int q = threadIdx.x & 7;                       // lane within pair-group
    if (i >= EC) return;
    int s = ld_idx32(eli, i, N);
    int d = ld_idx32(eli, (size_t)EC + i, N);
    float4 a = *reinterpret_cast<const float4*>(z + (size_t)s * 32 + q * 4);
    float4 b = *reinterpret_cast<const float4*>(z + (size_t)d * 32 + q * 4);
    float acc = a.x * b.x + a.y * b.y + a.z * b.z + a.w * b.w;
    acc += __shfl_xor(acc, 1);
    acc += __shfl_xor(acc, 2);
    acc += __shfl_xor(acc, 4);
    if (q == 0) outp[i] = acc;
}

static inline int cdiv(long long a, long long b) { return (int)((a + b - 1) / b); }

extern "C" void kernel_launch(void* const* d_in, const int* in_sizes, int n_in, void* d_out,
                              int out_size, void* d_ws, size_t ws_size, hipStream_t stream) {
    const float* x = (const float*)d_in[0];
    const int* ei = (const int*)d_in[1];
    const int* eli = (const int*)d_in[2];
    const float* W1 = (const float*)d_in[3];
    const float* a1s = (const float*)d_in[4];
    const float* a1d = (const float*)d_in[5];
    const float* b1 = (const float*)d_in[6];
    const float* W2 = (const float*)d_in[7];
    const float* a2s = (const float*)d_in[8];
    const float* a2d = (const float*)d_in[9];
    const float* b2 = (const float*)d_in[10];
    const float* W3 = (const float*)d_in[11];
    const float* a3s = (const float*)d_in[12];
    const float* a3d = (const float*)d_in[13];
    const float* b3 = (const float*)d_in[14];
    float* outp = (float*)d_out;

    const int N = in_sizes[0] / 384;
    const int E = in_sizes[1] / 2;
    int EC = in_sizes[2] / 2;
    if (out_size > 0 && out_size < EC) EC = out_size;
    const int ET = E + N;
    const int NBE = cdiv(ET, EPB);   // edge-blocks
    const int M = 256 * NBE;         // histogram entries (bucket-major)

    // ---- workspace (~72 MB) ----
    char* w = (char*)d_ws;
    size_t off = 0;
    auto alloc = [&](size_t bytes) {
        void* p = w + off;
        off += (bytes + 255) & ~(size_t)255;
        return p;
    };
    _Float16* hl = (_Float16*)alloc((size_t)N * 256 * 2);   // h_lin fp16 (per layer)
    _Float16* act = (_Float16*)alloc((size_t)N * 256 * 2);  // activations fp16
    float* z = (float*)alloc((size_t)N * 32 * 4);
    float* as_ = (float*)alloc((size_t)N * 4 * 4);
    float* ad_ = (float*)alloc((size_t)N * 4 * 4);
    int* rowptr = (int*)alloc((size_t)(N + 1) * 4);
    int* csr = (int*)alloc((size_t)ET * 4);
    int2* ep = (int2*)alloc((size_t)ET * 8);     // bucket-partitioned (s,d)
    int* histG = (int*)alloc((size_t)M * 4);
    int* histS = (int*)alloc((size_t)M * 4);
    int* part = (int*)alloc((size_t)cdiv(M, 256) * 4);
    _Float16* Wt1 = (_Float16*)alloc((size_t)384 * 256 * 2);
    _Float16* Wt2 = (_Float16*)alloc((size_t)256 * 64 * 2);
    _Float16* Wt3 = (_Float16*)alloc((size_t)64 * 128 * 2);

    if (off > ws_size) return;  // diagnostic: zero output -> absmax == max|ref|

    // CSR build (counting sort, LDS atomics only) + weight prep
    tr_k<<<cdiv(WTOT, 256), 256, 0, stream>>>(W1, W2, W3, Wt1, Wt2, Wt3);
    hist1_k<<<NBE, 256, 0, stream>>>(ei, E, N, histG, NBE);
    scan1_k<<<cdiv(M, 256), 256, 0, stream>>>(histG, part, M);
    scan2_k<<<cdiv(M, 256), 256, 0, stream>>>(histG, part, histS, M);
    scatter_k<<<NBE, 256, 0, stream>>>(ei, E, N, histS, NBE, ep);
    csrb_k<<<256, 256, 0, stream>>>(histS, NBE, ep, csr, rowptr, N, ET);

    const int gemm_blocks = cdiv(N, 64);
    const int quad_blocks = cdiv(N, 4);

    // ===== Layer 1: 384 -> 4x64 concat, ELU =====
    gemm_mfma<384, 256, 96, 64, true><<<gemm_blocks, 256, 0, stream>>>(x, Wt1, hl, a1s, a1d,
                                                                       as_, ad_, N);
    agg_csr<256, 0><<<quad_blocks, 256, 0, stream>>>(rowptr, csr, hl, as_, ad_, b1, act, N);
    // ===== Layer 2: 256 -> 4x16 concat, ELU =====
    gemm_mfma<256, 64, 256, 64, false><<<gemm_blocks, 256, 0, stream>>>(act, Wt2, hl, a2s, a2d,
                                                                        as_, ad_, N);
    agg_csr<64, 0><<<quad_blocks, 256, 0, stream>>>(rowptr, csr, hl, as_, ad_, b2, act, N);
    // ===== Layer 3: 64 -> 4x32, mean over heads (fused) =====
    gemm_mfma<64, 128, 64, 64, false><<<gemm_blocks, 256, 0, stream>>>(act, Wt3, hl, a3s, a3d,
                                                                       as_, ad_, N);
    agg_csr<128, 1><<<quad_blocks, 256, 0, stream>>>(rowptr, csr, hl, as_, ad_, b3, z, N);

    // ===== Decoder (fp32 logits) =====
    logits8_k<<<cdiv(EC, 32), 256, 0, stream>>>(eli, EC, N, z, outp);
}

// Round 17
// 383.072 us; speedup vs baseline: 1.0594x; 1.0594x over previous
//
#include <hip/hip_runtime.h>
#include <hip/hip_bf16.h>

// Resolved: x,W*,a*,b* fp32 | indices int32 | d_out FLOAT32.
// r13-r17: fused agg (shifted-exp softmax), fp16 pipeline, LDS-tiled MFMA GEMM
//          with fused alpha epilogue.
// r22/r26: gemm ILP fixes -> REGRESSION (no TLP to convert ILP into).
// r24: counter padding -> NO-OP. r25: counting-sort CSR build (-67us).
// r27: BM=64 grid doubling -> occupancy stuck 18%: LDS 53.2KB allows only 2
//      blocks/CU (3x53.2 = 159.7KB is over the limit with any reservation).
// r28: KC=48 -> BROKEN (KC not multiple of 32: kb=32 B-fragment read ran past
//      the padded row end -> NaN). Lesson: KC % 32 == 0 is a hard constraint.
// r29: legal LDS shrink: gemm1 KC=64 (36.9KB -> 4 blocks fit; grid-capped ~3
//      blocks/CU = ~37% occ), gemm2 KC=128 (17.4KB), gemm3 KC=64. BM=64 kept.
//      Bit-identical math vs r27.

using halfx8  = __attribute__((ext_vector_type(8))) _Float16;
using floatx4 = __attribute__((ext_vector_type(4))) float;

__device__ __forceinline__ float lrelu(float v) { return v > 0.f ? v : 0.2f * v; }

__device__ __forceinline__ int ld_idx32(const int* __restrict__ p, size_t i, int N) {
    int v = p[i];
    return ((unsigned)v < (unsigned)N) ? v : 0;
}
__device__ __forceinline__ void edge_sd(const int* __restrict__ ei, int E, int N, int e, int& s,
                                        int& d) {
    if (e < E) {
        s = ld_idx32(ei, e, N);
        d = ld_idx32(ei, (size_t)E + e, N);
    } else {
        s = d = e - E;  // self-loop
    }
}

#define WTOT (384 * 256 + 256 * 64 + 64 * 128)
#define EPB 4096  // edges per block in bucket passes

// ---------- weight transpose+convert: Wt[o][k] = f16(W[k][o]) ----------
__global__ void tr_k(const float* __restrict__ W1, const float* __restrict__ W2,
                     const float* __restrict__ W3, _Float16* __restrict__ Wt1,
                     _Float16* __restrict__ Wt2, _Float16* __restrict__ Wt3) {
    int j = blockIdx.x * 256 + threadIdx.x;
    if (j < 384 * 256) {
        int k = j / 256, o = j % 256;
        Wt1[(size_t)o * 384 + k] = (_Float16)W1[j];
    } else if (j < 384 * 256 + 256 * 64) {
        int jj = j - 384 * 256;
        int k = jj / 64, o = jj % 64;
        Wt2[(size_t)o * 256 + k] = (_Float16)W2[jj];
    } else if (j < WTOT) {
        int jj = j - (384 * 256 + 256 * 64);
        int k = jj / 128, o = jj % 128;
        Wt3[(size_t)o * 64 + k] = (_Float16)W3[jj];
    }
}

// ---------- CSR build: two-level counting sort, LDS atomics only ----------
// Requires N <= 65536 (bucket = d>>8 in [0,256)).
__global__ __launch_bounds__(256) void hist1_k(const int* __restrict__ ei, int E, int N,
                                               int* __restrict__ histG, int NBE) {
    __shared__ int h[256];
    const int t = threadIdx.x, b = blockIdx.x;
    h[t] = 0;
    __syncthreads();
    const int ET = E + N;
    const int base = b * EPB;
    for (int i = t; i < EPB; i += 256) {
        int e = base + i;
        if (e < ET) {
            int d = (e < E) ? ld_idx32(ei, (size_t)E + e, N) : (e - E);
            atomicAdd(&h[d >> 8], 1);
        }
    }
    __syncthreads();
    histG[(size_t)t * NBE + b] = h[t];  // bucket-major
}
// scan pass 1: per-256-chunk sums
__global__ void scan1_k(const int* __restrict__ a, int* __restrict__ part, int M) {
    __shared__ int sm[256];
    int t = threadIdx.x;
    int i = blockIdx.x * 256 + t;
    sm[t] = (i < M) ? a[i] : 0;
    __syncthreads();
    for (int off = 128; off > 0; off >>= 1) {
        if (t < off) sm[t] += sm[t + off];
        __syncthreads();
    }
    if (t == 0) part[blockIdx.x] = sm[0];
}
// scan pass 2: exclusive scan (block base = parallel sum of part[0..b))
__global__ void scan2_k(const int* __restrict__ a, const int* __restrict__ part,
                        int* __restrict__ out, int M) {
    __shared__ int sm[256];
    __shared__ int base_sh;
    const int t = threadIdx.x, b = blockIdx.x;
    int p = 0;
    for (int j = t; j < b; j += 256) p += part[j];
    sm[t] = p;
    __syncthreads();
    for (int off = 128; off > 0; off >>= 1) {
        if (t < off) sm[t] += sm[t + off];
        __syncthreads();
    }
    if (t == 0) base_sh = sm[0];
    __syncthreads();
    const int base = base_sh;
    int i = b * 256 + t;
    int v = (i < M) ? a[i] : 0;
    sm[t] = v;
    __syncthreads();
    for (int off = 1; off < 256; off <<= 1) {
        int add = (t >= off) ? sm[t - off] : 0;
        __syncthreads();
        sm[t] += add;
        __syncthreads();
    }
    if (i < M) out[i] = base + sm[t] - v;
}
// scatter edges into bucket-partitioned (s,d) pairs; LDS counters
__global__ __launch_bounds__(256) void scatter_k(const int* __restrict__ ei, int E, int N,
                                                 const int* __restrict__ histS, int NBE,
                                                 int2* __restrict__ ep) {
    __shared__ int ofs[256];
    const int t = threadIdx.x, b = blockIdx.x;
    ofs[t] = histS[(size_t)t * NBE + b];
    __syncthreads();
    const int ET = E + N;
    const int base = b * EPB;
    for (int i = t; i < EPB; i += 256) {
        int e = base + i;
        if (e < ET) {
            int s, d;
            edge_sd(ei, E, N, e, s, d);
            int pos = atomicAdd(&ofs[d >> 8], 1);
            ep[pos] = make_int2(s, d);
        }
    }
}
// per-bucket CSR: 256 dsts per block; LDS count + scan + place
__global__ __launch_bounds__(256) void csrb_k(const int* __restrict__ histS, int NBE,
                                              const int2* __restrict__ ep, int* __restrict__ csr,
                                              int* __restrict__ rowptr, int N, int ET) {
    __shared__ int cnt[256], rb[256], sm[256];
    const int t = threadIdx.x, c = blockIdx.x;
    const int lo = histS[(size_t)c * NBE];
    const int hi = (c + 1 < 256) ? histS[(size_t)(c + 1) * NBE] : ET;
    cnt[t] = 0;
    __syncthreads();
    for (int i = lo + t; i < hi; i += 256) atomicAdd(&cnt[ep[i].y & 255], 1);
    __syncthreads();
    int v = cnt[t];
    sm[t] = v;
    __syncthreads();
    for (int off = 1; off < 256; off <<= 1) {
        int add = (t >= off) ? sm[t - off] : 0;
        __syncthreads();
        sm[t] += add;
        __syncthreads();
    }
    rb[t] = lo + sm[t] - v;  // row base for dst c*256+t
    int dg = c * 256 + t;
    if (dg < N) rowptr[dg] = rb[t];
    if (dg == N - 1) rowptr[N] = ET;
    cnt[t] = 0;
    __syncthreads();
    for (int i = lo + t; i < hi; i += 256) {
        int2 e = ep[i];
        int d8 = e.y & 255;
        int p = atomicAdd(&cnt[d8], 1);
        csr[rb[d8] + p] = e.x;
    }
}

// ---------- LDS-tiled MFMA f16 GEMM + fused alpha epilogue ----------
// Block: 256 thr / 4 waves, BM rows (wave w owns rows blk*BM + w*(BM/4), MR=BM/64).
// Bt staged in LDS in K-chunks of KC (KC % 32 == 0!), rows padded +16B.
// Epilogue: C fp16 + per-row per-head dots with a_s/a_d -> alpha_s/alpha_d.
template <int K, int O, int KC, int BM, bool AF32>
__global__ __launch_bounds__(256, 2) void gemm_mfma(const void* __restrict__ A,
                                                    const _Float16* __restrict__ Bt,
                                                    _Float16* __restrict__ C,
                                                    const float* __restrict__ aw_s,
                                                    const float* __restrict__ aw_d,
                                                    float* __restrict__ alpha_s,
                                                    float* __restrict__ alpha_d, int M) {
    static_assert(KC % 32 == 0, "KC must be a multiple of the MFMA K-step");
    constexpr int MR = BM / 64;      // 16-row tiles per wave
    constexpr int NT = O / 16;
    constexpr int TPH = NT / 4;      // t-values per head
    constexpr int RB = KC * 2 + 16;  // padded LDS row bytes
    constexpr int SPR = KC / 8;      // 16B segments per row
    __shared__ __align__(16) char bs[O * RB];
    const int tid = threadIdx.x;
    const int wave = tid >> 6, lane = tid & 63;
    const int col = lane & 15, quad = lane >> 4;
    const int m0 = blockIdx.x * BM + wave * (MR * 16);
    int ar[MR];
#pragma unroll
    for (int m = 0; m < MR; ++m) {
        int r = m0 + m * 16 + col;
        ar[m] = (r < M) ? r : M - 1;  // clamp: clamped-row outputs are discarded
    }
    floatx4 acc[MR][NT];
#pragma unroll
    for (int m = 0; m < MR; ++m)
#pragma unroll
        for (int t = 0; t < NT; ++t) acc[m][t] = (floatx4){0.f, 0.f, 0.f, 0.f};
    const float* Af[MR];
    const _Float16* Ah[MR];
#pragma unroll
    for (int m = 0; m < MR; ++m) {
        Af[m] = reinterpret_cast<const float*>(A) + (size_t)ar[m] * K + quad * 8;
        Ah[m] = reinterpret_cast<const _Float16*>(A) + (size_t)ar[m] * K + quad * 8;
    }

    for (int kc = 0; kc < K; kc += KC) {
        __syncthreads();  // protect previous chunk's reads
        // cooperative stage: Bt[0..O)[kc..kc+KC) -> bs, row-major, padded rows
        for (int i = tid; i < O * SPR; i += 256) {
            int o = i / SPR, seg = i % SPR;
            float4 v = *reinterpret_cast<const float4*>(reinterpret_cast<const char*>(Bt) +
                                                        (size_t)o * (K * 2) + (size_t)kc * 2 +
                                                        seg * 16);
            *reinterpret_cast<float4*>(&bs[o * RB + seg * 16]) = v;
        }
        __syncthreads();
#pragma unroll
        for (int kb = 0; kb < KC; kb += 32) {
            halfx8 a[MR];
            if constexpr (AF32) {
#pragma unroll
                for (int m = 0; m < MR; ++m) {
                    float4 u = *reinterpret_cast<const float4*>(Af[m] + kc + kb);
                    float4 v = *reinterpret_cast<const float4*>(Af[m] + kc + kb + 4);
                    a[m][0] = (_Float16)u.x; a[m][1] = (_Float16)u.y;
                    a[m][2] = (_Float16)u.z; a[m][3] = (_Float16)u.w;
                    a[m][4] = (_Float16)v.x; a[m][5] = (_Float16)v.y;
                    a[m][6] = (_Float16)v.z; a[m][7] = (_Float16)v.w;
                }
            } else {
#pragma unroll
                for (int m = 0; m < MR; ++m)
                    a[m] = *reinterpret_cast<const halfx8*>(Ah[m] + kc + kb);
            }
#pragma unroll
            for (int t = 0; t < NT; ++t) {
                halfx8 b = *reinterpret_cast<const halfx8*>(
                    &bs[(size_t)(t * 16 + col) * RB + kb * 2 + quad * 16]);
#pragma unroll
                for (int m = 0; m < MR; ++m)
                    acc[m][t] = __builtin_amdgcn_mfma_f32_16x16x32_f16(a[m], b, acc[m][t], 0, 0, 0);
            }
        }
    }
    // C write (fp16)
#pragma unroll
    for (int m = 0; m < MR; ++m)
#pragma unroll
        for (int t = 0; t < NT; ++t)
#pragma unroll
            for (int r = 0; r < 4; ++r) {
                int row = m0 + m * 16 + quad * 4 + r;
                if (row < M) C[(size_t)row * O + t * 16 + col] = (_Float16)acc[m][t][r];
            }
    // fused alpha: per row, per head dots with a_s/a_d (flat index == channel o)
    float ws[NT], wd[NT];
#pragma unroll
    for (int t = 0; t < NT; ++t) {
        ws[t] = aw_s[t * 16 + col];
        wd[t] = aw_d[t * 16 + col];
    }
#pragma unroll
    for (int m = 0; m < MR; ++m)
#pragma unroll
        for (int r = 0; r < 4; ++r) {
            float sh[4] = {0.f, 0.f, 0.f, 0.f}, dh[4] = {0.f, 0.f, 0.f, 0.f};
#pragma unroll
            for (int t = 0; t < NT; ++t) {
                float v = acc[m][t][r];
                sh[t / TPH] = fmaf(v, ws[t], sh[t / TPH]);
                dh[t / TPH] = fmaf(v, wd[t], dh[t / TPH]);
            }
#pragma unroll
            for (int off = 1; off < 16; off <<= 1) {
#pragma unroll
                for (int hh = 0; hh < 4; ++hh) {
                    sh[hh] += __shfl_xor(sh[hh], off);
                    dh[hh] += __shfl_xor(dh[hh], off);
                }
            }
            int row = m0 + m * 16 + quad * 4 + r;
            if (col == 0 && row < M) {
                *reinterpret_cast<float4*>(alpha_s + (size_t)row * 4) =
                    make_float4(sh[0], sh[1], sh[2], sh[3]);
                *reinterpret_cast<float4*>(alpha_d + (size_t)row * 4) =
                    make_float4(dh[0], dh[1], dh[2], dh[3]);
            }
        }
}

// ---------- fused CSR attention: shifted-exp softmax (no max), fp16 gather ----------
// ex = exp(e - 16): scores bounded -> overflow-safe, alpha ratio unchanged.
// Denominator: per-lane partials, ONE butterfly at the end.
// Lane loads 8 halves (16B) of row lane/LPR; R=64/LPR rows per load instruction.
// MODE 0: +bias, ELU, fp16 out (layers 1,2). MODE 1: mean-over-heads +bias, fp32 z.
template <int O, int MODE>
__global__ __launch_bounds__(256) void agg_csr(const int* __restrict__ rowptr,
                                               const int* __restrict__ csr,
                                               const _Float16* __restrict__ h,
                                               const float* __restrict__ as_,
                                               const float* __restrict__ ad_,
                                               const float* __restrict__ bias,
                                               void* __restrict__ outp, int N) {
    constexpr int LPR = O / 8;   // lanes per row (8 halves = 16B each)
    constexpr int R = 64 / LPR;  // rows per load instruction (2/8/4 for O=256/64/128)
    constexpr int CH = O / 4;    // channels per head
    __shared__ float ex_lds[4][64][4];
    const int lane = threadIdx.x & 63;
    const int wave = threadIdx.x >> 6;
    const int d = blockIdx.x * 4 + wave;
    if (d >= N) return;
    const int g = lane / LPR;        // row subgroup
    const int c0 = (lane % LPR) * 8; // channel base (8 channels, all in one head)
    const int hd = c0 / CH;          // head of this lane's channels
    const int r0 = rowptr[d], r1 = rowptr[d + 1];
    const float4 adv = *reinterpret_cast<const float4*>(ad_ + (size_t)d * 4);

    float4 den_l = make_float4(0.f, 0.f, 0.f, 0.f);  // per-lane partial denominators
    float acc[8];
#pragma unroll
    for (int q = 0; q < 8; ++q) acc[q] = 0.f;
    float(&exw)[64][4] = ex_lds[wave];

    for (int base = r0; base < r1; base += 64) {
        const int cnt = min(64, r1 - base);
        const bool valid = lane < cnt;
        int s_l = 0;
        float4 av = make_float4(0.f, 0.f, 0.f, 0.f);
        if (valid) {
            s_l = csr[base + lane];
            av = *reinterpret_cast<const float4*>(as_ + (size_t)s_l * 4);
        }
        const int iters = (cnt + R - 1) / R;

        auto ldrow = [&](int i) -> halfx8 {
            int e = i * R + g;
            int idx = (e < cnt) ? e : (cnt - 1);
            int s = __shfl(s_l, idx);
            return *reinterpret_cast<const halfx8*>(h + (size_t)s * O + c0);
        };
        // issue first 4 row loads now: depend only on csr; overlap exp+LDS-write
        halfx8 b0 = ldrow(0), b1 = ldrow(1), b2 = ldrow(2), b3 = ldrow(3);

        float4 ex4 = make_float4(0.f, 0.f, 0.f, 0.f);
        if (valid) {
            ex4.x = __expf(lrelu(av.x + adv.x) - 16.f);
            ex4.y = __expf(lrelu(av.y + adv.y) - 16.f);
            ex4.z = __expf(lrelu(av.z + adv.z) - 16.f);
            ex4.w = __expf(lrelu(av.w + adv.w) - 16.f);
        }
        den_l.x += ex4.x; den_l.y += ex4.y; den_l.z += ex4.z; den_l.w += ex4.w;
        *reinterpret_cast<float4*>(&exw[lane][0]) = ex4;  // zeros past cnt

        auto accrow = [&](int i, halfx8 src) {
            int e = i * R + g;
            float ex = exw[e][hd];
#pragma unroll
            for (int q = 0; q < 8; ++q) acc[q] = fmaf(ex, (float)src[q], acc[q]);
        };
        int i = 0;
        for (; i + 4 < iters; i += 4) {
            accrow(i, b0);     b0 = ldrow(i + 4);
            accrow(i + 1, b1); b1 = ldrow(i + 5);
            accrow(i + 2, b2); b2 = ldrow(i + 6);
            accrow(i + 3, b3); b3 = ldrow(i + 7);
        }
        if (i < iters)     accrow(i, b0);
        if (i + 1 < iters) accrow(i + 1, b1);
        if (i + 2 < iters) accrow(i + 2, b2);
        if (i + 3 < iters) accrow(i + 3, b3);
    }

    // single denominator butterfly (all 4 heads), once per dst
#pragma unroll
    for (int off = 1; off < 64; off <<= 1) {
        den_l.x += __shfl_xor(den_l.x, off);
        den_l.y += __shfl_xor(den_l.y, off);
        den_l.z += __shfl_xor(den_l.z, off);
        den_l.w += __shfl_xor(den_l.w, off);
    }

    // fold cross-group partial sums (groups live in high lane bits)
#pragma unroll
    for (int q = 0; q < 8; ++q) {
        if constexpr (R >= 8) acc[q] += __shfl_xor(acc[q], 8);
        if constexpr (R >= 4) acc[q] += __shfl_xor(acc[q], 16);
        if constexpr (R >= 2) acc[q] += __shfl_xor(acc[q], 32);
    }

    float den = (hd == 0 ? den_l.x : (hd == 1 ? den_l.y : (hd == 2 ? den_l.z : den_l.w))) + 1e-30f;
    float v[8];
#pragma unroll
    for (int q = 0; q < 8; ++q) v[q] = acc[q] / den;

    if constexpr (MODE == 0) {  // +bias, ELU, fp16 act out
#pragma unroll
        for (int q = 0; q < 8; ++q) {
            float t = v[q] + bias[c0 + q];
            v[q] = t > 0.f ? t : (__expf(t) - 1.f);
        }
        if (g == 0) {
            halfx8 o;
#pragma unroll
            for (int q = 0; q < 8; ++q) o[q] = (_Float16)v[q];
            *reinterpret_cast<halfx8*>((_Float16*)outp + (size_t)d * O + c0) = o;
        }
    } else {  // MODE 1: mean over heads + bias -> fp32 z (O=128: heads at lane%16 stride 4)
#pragma unroll
        for (int q = 0; q < 8; ++q) {
            v[q] += __shfl_xor(v[q], 4);
            v[q] += __shfl_xor(v[q], 8);
        }
        if (lane < 4) {
            float* zp = (float*)outp + (size_t)d * 32 + lane * 8;
#pragma unroll
            for (int q = 0; q < 8; ++q) zp[q] = 0.25f * v[q] + bias[lane * 8 + q];
        }
    }
}

// ---------- decoder: 8 lanes per pair, coalesced float4 reads ----------
__global__ __launch_bounds__(256) void logits8_k(const int* __restrict__ eli, int EC, int N,
                                                 const float* __restrict__ z,
                                                 float* __restrict__ outp) {
    int i = blockIdx.x * 32 + (threadIdx.x >> 3);  // pair index
    int q = threadIdx.x & 7;                       // lane within pair-group
    if (i >= EC) return;
    int s = ld_idx32(eli, i, N);
    int d = ld_idx32(eli, (size_t)EC + i, N);
    float4 a = *reinterpret_cast<const float4*>(z + (size_t)s * 32 + q * 4);
    float4 b = *reinterpret_cast<const float4*>(z + (size_t)d * 32 + q * 4);
    float acc = a.x * b.x + a.y * b.y + a.z * b.z + a.w * b.w;
    acc += __shfl_xor(acc, 1);
    acc += __shfl_xor(acc, 2);
    acc += __shfl_xor(acc, 4);
    if (q == 0) outp[i] = acc;
}

static inline int cdiv(long long a, long long b) { return (int)((a + b - 1) / b); }

extern "C" void kernel_launch(void* const* d_in, const int* in_sizes, int n_in, void* d_out,
                              int out_size, void* d_ws, size_t ws_size, hipStream_t stream) {
    const float* x = (const float*)d_in[0];
    const int* ei = (const int*)d_in[1];
    const int* eli = (const int*)d_in[2];
    const float* W1 = (const float*)d_in[3];
    const float* a1s = (const float*)d_in[4];
    const float* a1d = (const float*)d_in[5];
    const float* b1 = (const float*)d_in[6];
    const float* W2 = (const float*)d_in[7];
    const float* a2s = (const float*)d_in[8];
    const float* a2d = (const float*)d_in[9];
    const float* b2 = (const float*)d_in[10];
    const float* W3 = (const float*)d_in[11];
    const float* a3s = (const float*)d_in[12];
    const float* a3d = (const float*)d_in[13];
    const float* b3 = (const float*)d_in[14];
    float* outp = (float*)d_out;

    const int N = in_sizes[0] / 384;
    const int E = in_sizes[1] / 2;
    int EC = in_sizes[2] / 2;
    if (out_size > 0 && out_size < EC) EC = out_size;
    const int ET = E + N;
    const int NBE = cdiv(ET, EPB);   // edge-blocks
    const int M = 256 * NBE;         // histogram entries (bucket-major)

    // ---- workspace (~72 MB) ----
    char* w = (char*)d_ws;
    size_t off = 0;
    auto alloc = [&](size_t bytes) {
        void* p = w + off;
        off += (bytes + 255) & ~(size_t)255;
        return p;
    };
    _Float16* hl = (_Float16*)alloc((size_t)N * 256 * 2);   // h_lin fp16 (per layer)
    _Float16* act = (_Float16*)alloc((size_t)N * 256 * 2);  // activations fp16
    float* z = (float*)alloc((size_t)N * 32 * 4);
    float* as_ = (float*)alloc((size_t)N * 4 * 4);
    float* ad_ = (float*)alloc((size_t)N * 4 * 4);
    int* rowptr = (int*)alloc((size_t)(N + 1) * 4);
    int* csr = (int*)alloc((size_t)ET * 4);
    int2* ep = (int2*)alloc((size_t)ET * 8);     // bucket-partitioned (s,d)
    int* histG = (int*)alloc((size_t)M * 4);
    int* histS = (int*)alloc((size_t)M * 4);
    int* part = (int*)alloc((size_t)cdiv(M, 256) * 4);
    _Float16* Wt1 = (_Float16*)alloc((size_t)384 * 256 * 2);
    _Float16* Wt2 = (_Float16*)alloc((size_t)256 * 64 * 2);
    _Float16* Wt3 = (_Float16*)alloc((size_t)64 * 128 * 2);

    if (off > ws_size) return;  // diagnostic: zero output -> absmax == max|ref|

    // CSR build (counting sort, LDS atomics only) + weight prep
    tr_k<<<cdiv(WTOT, 256), 256, 0, stream>>>(W1, W2, W3, Wt1, Wt2, Wt3);
    hist1_k<<<NBE, 256, 0, stream>>>(ei, E, N, histG, NBE);
    scan1_k<<<cdiv(M, 256), 256, 0, stream>>>(histG, part, M);
    scan2_k<<<cdiv(M, 256), 256, 0, stream>>>(histG, part, histS, M);
    scatter_k<<<NBE, 256, 0, stream>>>(ei, E, N, histS, NBE, ep);
    csrb_k<<<256, 256, 0, stream>>>(histS, NBE, ep, csr, rowptr, N, ET);

    const int gemm_blocks = cdiv(N, 64);
    const int quad_blocks = cdiv(N, 4);

    // ===== Layer 1: 384 -> 4x64 concat, ELU =====
    gemm_mfma<384, 256, 64, 64, true><<<gemm_blocks, 256, 0, stream>>>(x, Wt1, hl, a1s, a1d,
                                                                       as_, ad_, N);
    agg_csr<256, 0><<<quad_blocks, 256, 0, stream>>>(rowptr, csr, hl, as_, ad_, b1, act, N);
    // ===== Layer 2: 256 -> 4x16 concat, ELU =====
    gemm_mfma<256, 64, 128, 64, false><<<gemm_blocks, 256, 0, stream>>>(act, Wt2, hl, a2s, a2d,
                                                                        as_, ad_, N);
    agg_csr<64, 0><<<quad_blocks, 256, 0, stream>>>(rowptr, csr, hl, as_, ad_, b2, act, N);
    // ===== Layer 3: 64 -> 4x32, mean over heads (fused) =====
    gemm_mfma<64, 128, 64, 64, false><<<gemm_blocks, 256, 0, stream>>>(act, Wt3, hl, a3s, a3d,
                                                                       as_, ad_, N);
    agg_csr<128, 1><<<quad_blocks, 256, 0, stream>>>(rowptr, csr, hl, as_, ad_, b3, z, N);

    // ===== Decoder (fp32 logits) =====
    logits8_k<<<cdiv(EC, 32), 256, 0, stream>>>(eli, EC, N, z, outp);
}